// Round 4
// baseline (39698.605 us; speedup 1.0000x reference)
//
#include <hip/hip_runtime.h>
#include <hip/hip_bf16.h>

typedef __hip_bfloat16 bf16;

// flag f: 0 = bf16, 1 = fp32
static __device__ __forceinline__ float ldm(const void* p, long i, int f){
  return f ? ((const float*)p)[i] : __bfloat162float(((const bf16*)p)[i]);
}
static __device__ __forceinline__ void stm(void* p, long i, int f, float v){
  if(f) ((float*)p)[i] = v; else ((bf16*)p)[i] = __float2bfloat16(v);
}

// ---------------- input dtype detector (bit-level correct) ----------------
// Key fact: bf16 == top 16 bits of fp32. So two bf16s packed in a 32-bit word
// reinterpreted as fp32 inherit the UPPER bf16's exponent -> looks sane. The
// discriminating test is the LOW 16 bits: for bf16 data it's a real weight
// (|v| in (1e-7,100)); for fp32 data it's random mantissa bits -> bf16 with
// ~uniform exponent, sane only ~12% of the time. 64 probes, threshold 48.
__global__ void k_detect(const void* __restrict__ w, int* __restrict__ mode){
  if(blockIdx.x == 0 && threadIdx.x == 0){
    const unsigned int* u = (const unsigned int*)w;
    int saneLo = 0;
    for(int i = 0; i < 64; i++){
      unsigned short lo = (unsigned short)(u[i] & 0xFFFFu);
      unsigned int fw = ((unsigned int)lo) << 16;
      float v; __builtin_memcpy(&v, &fw, 4);
      float a = fabsf(v);
      if(a > 1e-7f && a < 100.f) saneLo++;
    }
    *mode = (saneLo >= 48) ? 0 : 1;   // 0 = bf16, 1 = fp32
  }
}

// ---------------- direct conv 3x3, pad 1, stride S ----------------
template<int S>
__global__ void k_conv3x3(const void* __restrict__ in, long in_off, int fin_sel,
                          const void* __restrict__ w, const void* __restrict__ bias,
                          void* __restrict__ out, int fout,
                          const int* __restrict__ dmode,
                          int B, int Cin, int Hin, int Win, int Cout, int Hout, int Wout)
{
  long idx = (long)blockIdx.x * 256 + threadIdx.x;
  long total = (long)B * Cout * Hout * Wout;
  if(idx >= total) return;
  int dm = *dmode;
  int fin = (fin_sel == 2) ? dm : fin_sel;
  int wo = (int)(idx % Wout); long t = idx / Wout;
  int ho = (int)(t % Hout);   t /= Hout;
  int co = (int)(t % Cout);   int b = (int)(t / Cout);
  float acc = ldm(bias, co, dm);
  int hbase = ho * S - 1, wbase = wo * S - 1;
  long wbi = (long)co * Cin * 9;
  long ibase = in_off + (long)b * Cin * Hin * Win;
  for(int ci = 0; ci < Cin; ci++){
    long ip = ibase + (long)ci * Hin * Win;
    long wp = wbi + (long)ci * 9;
    #pragma unroll
    for(int kh = 0; kh < 3; kh++){
      int hi = hbase + kh;
      if((unsigned)hi >= (unsigned)Hin) continue;
      long rp = ip + (long)hi * Win;
      #pragma unroll
      for(int kw = 0; kw < 3; kw++){
        int wi = wbase + kw;
        if((unsigned)wi >= (unsigned)Win) continue;
        acc += ldm(in, rp + wi, fin) * ldm(w, wp + kh*3 + kw, dm);
      }
    }
  }
  stm(out, idx, fout, acc);
}

// ---------------- InstanceNorm (affine=False) + PReLU, in place ----------------
__global__ void k_inorm_prelu(void* __restrict__ x, int f, int HW,
                              const void* __restrict__ a, const int* __restrict__ dmode)
{
  int dm = *dmode;
  long base = (long)blockIdx.x * HW;
  float s = 0.f, s2 = 0.f;
  for(int i = threadIdx.x; i < HW; i += 256){ float v = ldm(x, base + i, f); s += v; s2 += v*v; }
  __shared__ float sh[256], sh2[256];
  sh[threadIdx.x] = s; sh2[threadIdx.x] = s2; __syncthreads();
  for(int off = 128; off > 0; off >>= 1){
    if(threadIdx.x < off){ sh[threadIdx.x] += sh[threadIdx.x+off]; sh2[threadIdx.x] += sh2[threadIdx.x+off]; }
    __syncthreads();
  }
  float mean = sh[0] / HW;
  float var  = sh2[0] / HW - mean * mean;
  float inv  = rsqrtf(fmaxf(var, 0.f) + 1e-5f);
  float alpha = ldm(a, 0, dm);
  for(int i = threadIdx.x; i < HW; i += 256){
    float v = (ldm(x, base + i, f) - mean) * inv;
    stm(x, base + i, f, v >= 0.f ? v : alpha * v);
  }
}

// ---------------- transpose [B,C,N] -> [B,N,C] (fp32) ----------------
__global__ void k_transpose(const float* __restrict__ in, float* __restrict__ out, int B, int C, int N){
  long idx = (long)blockIdx.x * 256 + threadIdx.x;
  long total = (long)B * C * N; if(idx >= total) return;
  int c = (int)(idx % C); long t = idx / C; int n = (int)(t % N); int b = (int)(t / N);
  out[idx] = in[((long)b * C + c) * N + n];
}

// ---------------- degree ----------------
__global__ void k_deg(const int* __restrict__ tgt, float* __restrict__ deg, int E){
  int e = blockIdx.x * 256 + threadIdx.x;
  if(e < E) atomicAdd(&deg[tgt[e]], 1.0f);
}

// ---------------- scatter add: agg[b,tgt,c] += x[b,src,c]  ([B,N,C] fp32) ----------------
__global__ void k_scatter(const float* __restrict__ xT, const int* __restrict__ src,
                          const int* __restrict__ tgt, float* __restrict__ agg,
                          int E, int C, int N, int B)
{
  int t = blockIdx.x * 256 + threadIdx.x;
  if(t >= E * C) return;
  int c = t % C; int e = t / C;
  int s = src[e], d = tgt[e];
  for(int b = 0; b < B; b++){
    atomicAdd(&agg[((long)b * N + d) * C + c], xT[((long)b * N + s) * C + c]);
  }
}

// ---------------- SAGE: relu(lin_l(agg/deg) + bl + lin_r(x)) ----------------
__global__ void k_sage(const float* __restrict__ xT, const float* __restrict__ agg,
                       const float* __restrict__ deg,
                       const void* __restrict__ wl, const void* __restrict__ bl,
                       const void* __restrict__ wr,
                       float* __restrict__ out, const int* __restrict__ dmode,
                       int B, int N, int C, int transpose_out)
{
  long idx = (long)blockIdx.x * 256 + threadIdx.x;
  long total = (long)B * N * C; if(idx >= total) return;
  int dm = *dmode;
  int o = (int)(idx % C); long t = idx / C; int n = (int)(t % N); int b = (int)(t / N);
  const float* xa = xT  + ((long)b * N + n) * C;
  const float* ag = agg + ((long)b * N + n) * C;
  float dinv = 1.0f / fmaxf(deg[n], 1.0f);
  float acc = ldm(bl, o, dm);
  long wro = (long)o * C;
  for(int c = 0; c < C; c++){
    acc += ag[c] * dinv * ldm(wl, wro + c, dm) + xa[c] * ldm(wr, wro + c, dm);
  }
  acc = fmaxf(acc, 0.f);
  if(transpose_out) out[((long)b * C + o) * N + n] = acc;
  else              out[idx] = acc;
}

// ---------------- ConvTranspose2d k=3, stride 2, pad 1, outpad 1 ----------------
// input = concat(inA [C1 ch], inB [C2 ch]); weight layout [Cin, Cout, 3, 3]
__global__ void k_convT(const void* __restrict__ inA, int fA, int C1,
                        const void* __restrict__ inB, int fB, int C2,
                        const void* __restrict__ w, const void* __restrict__ bias,
                        void* __restrict__ out, long out_off, int fout_sel,
                        const int* __restrict__ dmode,
                        int B, int Hin, int Win, int Cout, int Hout, int Wout)
{
  long idx = (long)blockIdx.x * 256 + threadIdx.x;
  long total = (long)B * Cout * Hout * Wout;
  if(idx >= total) return;
  int dm = *dmode;
  int fout = (fout_sel == 2) ? dm : fout_sel;
  int wo = (int)(idx % Wout); long t = idx / Wout;
  int ho = (int)(t % Hout);   t /= Hout;
  int co = (int)(t % Cout);   int b = (int)(t / Cout);
  float acc = ldm(bias, co, dm);
  int khs[2], his[2], nh = 0;
  #pragma unroll
  for(int kh = 0; kh < 3; kh++){
    int tt = ho + 1 - kh;
    if(tt & 1) continue;
    int hi = tt >> 1;
    if(hi < 0 || hi >= Hin) continue;
    khs[nh] = kh; his[nh] = hi; nh++;
  }
  int kws[2], wis[2], nw = 0;
  #pragma unroll
  for(int kw = 0; kw < 3; kw++){
    int tt = wo + 1 - kw;
    if(tt & 1) continue;
    int wi = tt >> 1;
    if(wi < 0 || wi >= Win) continue;
    kws[nw] = kw; wis[nw] = wi; nw++;
  }
  for(int ci = 0; ci < C1; ci++){
    long ip = ((long)b * C1 + ci) * Hin * Win;
    long wp = ((long)ci * Cout + co) * 9;
    for(int i = 0; i < nh; i++){
      long rp = ip + (long)his[i] * Win;
      for(int j = 0; j < nw; j++)
        acc += ldm(inA, rp + wis[j], fA) * ldm(w, wp + khs[i]*3 + kws[j], dm);
    }
  }
  for(int ci = 0; ci < C2; ci++){
    long ip = ((long)b * C2 + ci) * Hin * Win;
    long wp = ((long)(C1 + ci) * Cout + co) * 9;
    for(int i = 0; i < nh; i++){
      long rp = ip + (long)his[i] * Win;
      for(int j = 0; j < nw; j++)
        acc += ldm(inB, rp + wis[j], fB) * ldm(w, wp + khs[i]*3 + kws[j], dm);
    }
  }
  stm(out, out_off + idx, fout, acc);
}

static inline int cdiv(long a, long b){ return (int)((a + b - 1) / b); }

extern "C" void kernel_launch(void* const* d_in, const int* in_sizes, int n_in,
                              void* d_out, int out_size, void* d_ws, size_t ws_size,
                              hipStream_t stream) {
  const void* x_in  = d_in[0];
  const int*  edges = (const int*)d_in[1];
  const int* src = edges;          // edges[0,:]
  const int* tgt = edges + 5000;   // edges[1,:]
  const void *w_d4=d_in[2],  *b_d4=d_in[3],  *a_d4=d_in[4];
  const void *w_d3=d_in[5],  *b_d3=d_in[6],  *a_d3=d_in[7];
  const void *w_d2=d_in[8],  *b_d2=d_in[9],  *a_d2=d_in[10];
  const void *w_d1=d_in[11], *b_d1=d_in[12], *a_d1=d_in[13];
  const void *w_bot=d_in[14],*b_bot=d_in[15],*a_bot=d_in[16];
  const void *wl1=d_in[17], *bl1=d_in[18], *wr1=d_in[19];
  const void *wl2=d_in[20], *bl2=d_in[21], *wr2=d_in[22];
  const void *w_u1=d_in[23], *b_u1=d_in[24], *a_u1=d_in[25];
  const void *w_u2=d_in[26], *b_u2=d_in[27], *a_u2=d_in[28];
  const void *w_u3=d_in[29], *b_u3=d_in[30], *a_u3=d_in[31];
  const void *w_u4=d_in[32], *b_u4=d_in[33];

  const int NNODE = 625, E = 5000, CG = 256;

  // ---- batch-chunked, ws_size-adaptive layout (7.68 MB per batch element) ----
  int Bc = 16;
  while(Bc > 1 && (7680000L * Bc + 4096) > (long)ws_size) Bc >>= 1;

  char* wsb = (char*)d_ws;
  long o_xs1  = 2560000L * Bc;
  long o_BIGA = 3840000L * Bc;
  long o_BIGB = 6400000L * Bc;
  long o_deg  = 7680000L * Bc;
  bf16*  xs0 = (bf16*)wsb;                             // 1,280,000*Bc bf16  [d4 -> u4]
  bf16*  xs1 = (bf16*)(wsb + o_xs1);                   //   640,000*Bc bf16  [d3 -> u3]
  bf16*  xs2 = (bf16*)(wsb + o_BIGA);                  //   320,000*Bc bf16  [d2 -> u2]
  bf16*  xs3 = (bf16*)(wsb + o_BIGA +  640000L*Bc);    //   160,000*Bc bf16  [d1 -> u1]
  float* bot = (float*)(wsb + o_BIGA +  960000L*Bc);   //   160,000*Bc fp32  [bot -> u1] (=g2)
  float* xT  = (float*)(wsb + o_BIGA + 1600000L*Bc);   //   160,000*Bc fp32  [tr -> sage1]
  bf16*  u1  = (bf16*)(wsb + o_BIGA + 1600000L*Bc);    // alias xT (dead)    [u1 -> u2]
  bf16*  u3  = (bf16*)(wsb + o_BIGA);                  // alias BIGA (dead)  [u3 -> u4]
  float* agg = (float*)(wsb + o_BIGB);                 //   160,000*Bc fp32
  float* g1  = (float*)(wsb + o_BIGB +  640000L*Bc);   //   160,000*Bc fp32  [sage1 -> sage2]
  bf16*  u2  = (bf16*)(wsb + o_BIGB);                  // alias agg+g1 (dead)[u2 -> u3]
  float* deg = (float*)(wsb + o_deg);                  //   625 fp32
  int*  mode = (int*)(wsb + o_deg + 3072);
  float* g2  = bot;

  hipLaunchKernelGGL(k_detect, dim3(1), dim3(1), 0, stream, w_d4, mode);

  for(int bo = 0; bo < 16; bo += Bc){
    long x_off   = (long)bo * 160000;   // 400*400 per sample
    long out_off = (long)bo * 320000;   // 2*400*400 per sample

    // ---- encoder ----
    { long n = (long)Bc*32*200*200;
      hipLaunchKernelGGL((k_conv3x3<2>), dim3(cdiv(n,256)), dim3(256), 0, stream,
                         x_in, x_off, 2, w_d4, b_d4, xs0, 0, mode, Bc, 1, 400, 400, 32, 200, 200);
      hipLaunchKernelGGL(k_inorm_prelu, dim3(Bc*32), dim3(256), 0, stream, xs0, 0, 40000, a_d4, mode); }
    { long n = (long)Bc*64*100*100;
      hipLaunchKernelGGL((k_conv3x3<2>), dim3(cdiv(n,256)), dim3(256), 0, stream,
                         xs0, 0, 0, w_d3, b_d3, xs1, 0, mode, Bc, 32, 200, 200, 64, 100, 100);
      hipLaunchKernelGGL(k_inorm_prelu, dim3(Bc*64), dim3(256), 0, stream, xs1, 0, 10000, a_d3, mode); }
    { long n = (long)Bc*128*50*50;
      hipLaunchKernelGGL((k_conv3x3<2>), dim3(cdiv(n,256)), dim3(256), 0, stream,
                         xs1, 0, 0, w_d2, b_d2, xs2, 0, mode, Bc, 64, 100, 100, 128, 50, 50);
      hipLaunchKernelGGL(k_inorm_prelu, dim3(Bc*128), dim3(256), 0, stream, xs2, 0, 2500, a_d2, mode); }
    { long n = (long)Bc*256*25*25;
      hipLaunchKernelGGL((k_conv3x3<2>), dim3(cdiv(n,256)), dim3(256), 0, stream,
                         xs2, 0, 0, w_d1, b_d1, xs3, 0, mode, Bc, 128, 50, 50, 256, 25, 25);
      hipLaunchKernelGGL(k_inorm_prelu, dim3(Bc*256), dim3(256), 0, stream, xs3, 0, 625, a_d1, mode); }
    { long n = (long)Bc*256*25*25;
      hipLaunchKernelGGL((k_conv3x3<1>), dim3(cdiv(n,256)), dim3(256), 0, stream,
                         xs3, 0, 0, w_bot, b_bot, bot, 1, mode, Bc, 256, 25, 25, 256, 25, 25);
      hipLaunchKernelGGL(k_inorm_prelu, dim3(Bc*256), dim3(256), 0, stream, bot, 1, 625, a_bot, mode); }

    // ---- GNN ----
    { long n = (long)Bc*CG*NNODE;
      hipLaunchKernelGGL(k_transpose, dim3(cdiv(n,256)), dim3(256), 0, stream, bot, xT, Bc, CG, NNODE); }
    hipMemsetAsync(deg, 0, NNODE*sizeof(float), stream);
    hipLaunchKernelGGL(k_deg, dim3(cdiv(E,256)), dim3(256), 0, stream, tgt, deg, E);
    hipMemsetAsync(agg, 0, 640000L*Bc, stream);
    hipLaunchKernelGGL(k_scatter, dim3(cdiv((long)E*CG,256)), dim3(256), 0, stream, xT, src, tgt, agg, E, CG, NNODE, Bc);
    { long n = (long)Bc*NNODE*CG;
      hipLaunchKernelGGL(k_sage, dim3(cdiv(n,256)), dim3(256), 0, stream, xT, agg, deg, wl1, bl1, wr1, g1, mode, Bc, NNODE, CG, 0); }
    hipMemsetAsync(agg, 0, 640000L*Bc, stream);
    hipLaunchKernelGGL(k_scatter, dim3(cdiv((long)E*CG,256)), dim3(256), 0, stream, g1, src, tgt, agg, E, CG, NNODE, Bc);
    { long n = (long)Bc*NNODE*CG;
      hipLaunchKernelGGL(k_sage, dim3(cdiv(n,256)), dim3(256), 0, stream, g1, agg, deg, wl2, bl2, wr2, g2, mode, Bc, NNODE, CG, 1); }

    // ---- decoder ----
    { long n = (long)Bc*128*50*50;
      hipLaunchKernelGGL(k_convT, dim3(cdiv(n,256)), dim3(256), 0, stream,
                         xs3, 0, 256, g2, 1, 256, w_u1, b_u1, u1, 0L, 0, mode, Bc, 25, 25, 128, 50, 50);
      hipLaunchKernelGGL(k_inorm_prelu, dim3(Bc*128), dim3(256), 0, stream, u1, 0, 2500, a_u1, mode); }
    { long n = (long)Bc*64*100*100;
      hipLaunchKernelGGL(k_convT, dim3(cdiv(n,256)), dim3(256), 0, stream,
                         xs2, 0, 128, u1, 0, 128, w_u2, b_u2, u2, 0L, 0, mode, Bc, 50, 50, 64, 100, 100);
      hipLaunchKernelGGL(k_inorm_prelu, dim3(Bc*64), dim3(256), 0, stream, u2, 0, 10000, a_u2, mode); }
    { long n = (long)Bc*32*200*200;
      hipLaunchKernelGGL(k_convT, dim3(cdiv(n,256)), dim3(256), 0, stream,
                         xs1, 0, 64, u2, 0, 64, w_u3, b_u3, u3, 0L, 0, mode, Bc, 100, 100, 32, 200, 200);
      hipLaunchKernelGGL(k_inorm_prelu, dim3(Bc*32), dim3(256), 0, stream, u3, 0, 40000, a_u3, mode); }
    { long n = (long)Bc*2*400*400;   // final: output dtype resolved from runtime mode
      hipLaunchKernelGGL(k_convT, dim3(cdiv(n,256)), dim3(256), 0, stream,
                         xs0, 0, 32, u3, 0, 32, w_u4, b_u4, d_out, out_off, 2, mode, Bc, 200, 200, 2, 400, 400); }
  }
}

// Round 5
// 30133.789 us; speedup vs baseline: 1.3174x; 1.3174x over previous
//
#include <hip/hip_runtime.h>
#include <hip/hip_bf16.h>

typedef __hip_bfloat16 bf16;

// flag f: 0 = bf16, 1 = fp32
static __device__ __forceinline__ float ldm(const void* p, long i, int f){
  return f ? ((const float*)p)[i] : __bfloat162float(((const bf16*)p)[i]);
}
static __device__ __forceinline__ void stm(void* p, long i, int f, float v){
  if(f) ((float*)p)[i] = v; else ((bf16*)p)[i] = __float2bfloat16(v);
}

// ---------------- input dtype detector (bit-level correct) ----------------
// bf16 == top 16 bits of fp32, so test the LOW 16 bits of each 32-bit word:
// bf16 data -> real weight there (|v| sane); fp32 data -> random mantissa bits
// -> ~uniform exponent, sane ~12%.
__global__ void k_detect(const void* __restrict__ w, int* __restrict__ mode){
  if(blockIdx.x == 0 && threadIdx.x == 0){
    const unsigned int* u = (const unsigned int*)w;
    int saneLo = 0;
    for(int i = 0; i < 64; i++){
      unsigned short lo = (unsigned short)(u[i] & 0xFFFFu);
      unsigned int fw = ((unsigned int)lo) << 16;
      float v; __builtin_memcpy(&v, &fw, 4);
      float a = fabsf(v);
      if(a > 1e-7f && a < 100.f) saneLo++;
    }
    *mode = (saneLo >= 48) ? 0 : 1;   // 0 = bf16, 1 = fp32
  }
}

// ---------------- weight transpose: wT[c][o] = w[o][c], fp32 out ----------------
__global__ void k_wtrans(const void* __restrict__ w, float* __restrict__ wT,
                         const int* __restrict__ dmode, int C){
  int idx = blockIdx.x * 256 + threadIdx.x;
  if(idx >= C * C) return;
  int dm = *dmode;
  int o = idx % C, c = idx / C;           // out index: c-major, o fastest (coalesced)
  wT[idx] = ldm(w, (long)o * C + c, dm);
}

// ---------------- direct conv 3x3, pad 1, stride S ----------------
template<int S>
__global__ void k_conv3x3(const void* __restrict__ in, long in_off, int fin_sel,
                          const void* __restrict__ w, const void* __restrict__ bias,
                          void* __restrict__ out, int fout,
                          const int* __restrict__ dmode,
                          int B, int Cin, int Hin, int Win, int Cout, int Hout, int Wout)
{
  long idx = (long)blockIdx.x * 256 + threadIdx.x;
  long total = (long)B * Cout * Hout * Wout;
  if(idx >= total) return;
  int dm = *dmode;
  int fin = (fin_sel == 2) ? dm : fin_sel;
  int wo = (int)(idx % Wout); long t = idx / Wout;
  int ho = (int)(t % Hout);   t /= Hout;
  int co = (int)(t % Cout);   int b = (int)(t / Cout);
  float acc = ldm(bias, co, dm);
  int hbase = ho * S - 1, wbase = wo * S - 1;
  long wbi = (long)co * Cin * 9;
  long ibase = in_off + (long)b * Cin * Hin * Win;
  for(int ci = 0; ci < Cin; ci++){
    long ip = ibase + (long)ci * Hin * Win;
    long wp = wbi + (long)ci * 9;
    #pragma unroll
    for(int kh = 0; kh < 3; kh++){
      int hi = hbase + kh;
      if((unsigned)hi >= (unsigned)Hin) continue;
      long rp = ip + (long)hi * Win;
      #pragma unroll
      for(int kw = 0; kw < 3; kw++){
        int wi = wbase + kw;
        if((unsigned)wi >= (unsigned)Win) continue;
        acc += ldm(in, rp + wi, fin) * ldm(w, wp + kh*3 + kw, dm);
      }
    }
  }
  stm(out, idx, fout, acc);
}

// ---------------- InstanceNorm (affine=False) + PReLU, in place ----------------
__global__ void k_inorm_prelu(void* __restrict__ x, int f, int HW,
                              const void* __restrict__ a, const int* __restrict__ dmode)
{
  int dm = *dmode;
  long base = (long)blockIdx.x * HW;
  float s = 0.f, s2 = 0.f;
  for(int i = threadIdx.x; i < HW; i += 256){ float v = ldm(x, base + i, f); s += v; s2 += v*v; }
  __shared__ float sh[256], sh2[256];
  sh[threadIdx.x] = s; sh2[threadIdx.x] = s2; __syncthreads();
  for(int off = 128; off > 0; off >>= 1){
    if(threadIdx.x < off){ sh[threadIdx.x] += sh[threadIdx.x+off]; sh2[threadIdx.x] += sh2[threadIdx.x+off]; }
    __syncthreads();
  }
  float mean = sh[0] / HW;
  float var  = sh2[0] / HW - mean * mean;
  float inv  = rsqrtf(fmaxf(var, 0.f) + 1e-5f);
  float alpha = ldm(a, 0, dm);
  for(int i = threadIdx.x; i < HW; i += 256){
    float v = (ldm(x, base + i, f) - mean) * inv;
    stm(x, base + i, f, v >= 0.f ? v : alpha * v);
  }
}

// ---------------- transpose [B,C,N] -> [B,N,C] (fp32) ----------------
__global__ void k_transpose(const float* __restrict__ in, float* __restrict__ out, int B, int C, int N){
  long idx = (long)blockIdx.x * 256 + threadIdx.x;
  long total = (long)B * C * N; if(idx >= total) return;
  int c = (int)(idx % C); long t = idx / C; int n = (int)(t % N); int b = (int)(t / N);
  out[idx] = in[((long)b * C + c) * N + n];
}

// ---------------- degree ----------------
__global__ void k_deg(const int* __restrict__ tgt, float* __restrict__ deg, int E){
  int e = blockIdx.x * 256 + threadIdx.x;
  if(e < E) atomicAdd(&deg[tgt[e]], 1.0f);
}

// ---------------- scatter add: agg[b,tgt,c] += x[b,src,c]  ([B,N,C] fp32) ----------------
__global__ void k_scatter(const float* __restrict__ xT, const int* __restrict__ src,
                          const int* __restrict__ tgt, float* __restrict__ agg,
                          int E, int C, int N, int B)
{
  int t = blockIdx.x * 256 + threadIdx.x;
  if(t >= E * C) return;
  int c = t % C; int e = t / C;
  int s = src[e], d = tgt[e];
  for(int b = 0; b < B; b++){
    atomicAdd(&agg[((long)b * N + d) * C + c], xT[((long)b * N + s) * C + c]);
  }
}

// ---------------- SAGE as tiled GEMM ----------------
// grid (N/TN, B), block 256 (thread = output channel o). TN=5 (625=125*5).
// Weights pre-transposed fp32: wT[c][o] -> lane-coalesced loads, c wave-uniform.
// out[n][o] = relu( bl[o] + sum_c agg'[n][c]*wl[o][c] + x[n][c]*wr[o][c] )
#define TN 5
__global__ void k_sage2(const float* __restrict__ xT, const float* __restrict__ agg,
                        const float* __restrict__ deg,
                        const float* __restrict__ wlT, const float* __restrict__ wrT,
                        const void* __restrict__ bl,
                        float* __restrict__ out, const int* __restrict__ dmode,
                        int B, int N, int C, int transpose_out)
{
  int o  = threadIdx.x;
  int n0 = blockIdx.x * TN;
  int b  = blockIdx.y;
  __shared__ float sX[TN][256];
  __shared__ float sA[TN][256];
  #pragma unroll
  for(int j = 0; j < TN; j++){
    int n = n0 + j;
    float dinv = 1.0f / fmaxf(deg[n], 1.0f);
    long base = ((long)b * N + n) * C;
    sX[j][o] = xT[base + o];
    sA[j][o] = agg[base + o] * dinv;
  }
  __syncthreads();
  int dm = *dmode;
  float bv = ldm(bl, o, dm);
  float acc[TN];
  #pragma unroll
  for(int j = 0; j < TN; j++) acc[j] = bv;
  #pragma unroll 4
  for(int c = 0; c < 256; c++){
    float wlv = wlT[(long)c * 256 + o];
    float wrv = wrT[(long)c * 256 + o];
    #pragma unroll
    for(int j = 0; j < TN; j++){
      acc[j] += sA[j][c] * wlv + sX[j][c] * wrv;
    }
  }
  #pragma unroll
  for(int j = 0; j < TN; j++){
    int n = n0 + j;
    float v = fmaxf(acc[j], 0.f);
    if(transpose_out) out[((long)b * C + o) * N + n] = v;
    else              out[((long)b * N + n) * C + o] = v;
  }
}

// ---------------- ConvTranspose2d k=3, stride 2, pad 1, outpad 1 ----------------
// input = concat(inA [C1 ch], inB [C2 ch]); weight layout [Cin, Cout, 3, 3]
__global__ void k_convT(const void* __restrict__ inA, int fA, int C1,
                        const void* __restrict__ inB, int fB, int C2,
                        const void* __restrict__ w, const void* __restrict__ bias,
                        void* __restrict__ out, long out_off, int fout_sel,
                        const int* __restrict__ dmode,
                        int B, int Hin, int Win, int Cout, int Hout, int Wout)
{
  long idx = (long)blockIdx.x * 256 + threadIdx.x;
  long total = (long)B * Cout * Hout * Wout;
  if(idx >= total) return;
  int dm = *dmode;
  int fout = (fout_sel == 2) ? dm : fout_sel;
  int wo = (int)(idx % Wout); long t = idx / Wout;
  int ho = (int)(t % Hout);   t /= Hout;
  int co = (int)(t % Cout);   int b = (int)(t / Cout);
  float acc = ldm(bias, co, dm);
  int khs[2], his[2], nh = 0;
  #pragma unroll
  for(int kh = 0; kh < 3; kh++){
    int tt = ho + 1 - kh;
    if(tt & 1) continue;
    int hi = tt >> 1;
    if(hi < 0 || hi >= Hin) continue;
    khs[nh] = kh; his[nh] = hi; nh++;
  }
  int kws[2], wis[2], nw = 0;
  #pragma unroll
  for(int kw = 0; kw < 3; kw++){
    int tt = wo + 1 - kw;
    if(tt & 1) continue;
    int wi = tt >> 1;
    if(wi < 0 || wi >= Win) continue;
    kws[nw] = kw; wis[nw] = wi; nw++;
  }
  for(int ci = 0; ci < C1; ci++){
    long ip = ((long)b * C1 + ci) * Hin * Win;
    long wp = ((long)ci * Cout + co) * 9;
    for(int i = 0; i < nh; i++){
      long rp = ip + (long)his[i] * Win;
      for(int j = 0; j < nw; j++)
        acc += ldm(inA, rp + wis[j], fA) * ldm(w, wp + khs[i]*3 + kws[j], dm);
    }
  }
  for(int ci = 0; ci < C2; ci++){
    long ip = ((long)b * C2 + ci) * Hin * Win;
    long wp = ((long)(C1 + ci) * Cout + co) * 9;
    for(int i = 0; i < nh; i++){
      long rp = ip + (long)his[i] * Win;
      for(int j = 0; j < nw; j++)
        acc += ldm(inB, rp + wis[j], fB) * ldm(w, wp + khs[i]*3 + kws[j], dm);
    }
  }
  stm(out, out_off + idx, fout, acc);
}

static inline int cdiv(long a, long b){ return (int)((a + b - 1) / b); }

extern "C" void kernel_launch(void* const* d_in, const int* in_sizes, int n_in,
                              void* d_out, int out_size, void* d_ws, size_t ws_size,
                              hipStream_t stream) {
  const void* x_in  = d_in[0];
  const int*  edges = (const int*)d_in[1];
  const int* src = edges;          // edges[0,:]
  const int* tgt = edges + 5000;   // edges[1,:]
  const void *w_d4=d_in[2],  *b_d4=d_in[3],  *a_d4=d_in[4];
  const void *w_d3=d_in[5],  *b_d3=d_in[6],  *a_d3=d_in[7];
  const void *w_d2=d_in[8],  *b_d2=d_in[9],  *a_d2=d_in[10];
  const void *w_d1=d_in[11], *b_d1=d_in[12], *a_d1=d_in[13];
  const void *w_bot=d_in[14],*b_bot=d_in[15],*a_bot=d_in[16];
  const void *wl1=d_in[17], *bl1=d_in[18], *wr1=d_in[19];
  const void *wl2=d_in[20], *bl2=d_in[21], *wr2=d_in[22];
  const void *w_u1=d_in[23], *b_u1=d_in[24], *a_u1=d_in[25];
  const void *w_u2=d_in[26], *b_u2=d_in[27], *a_u2=d_in[28];
  const void *w_u3=d_in[29], *b_u3=d_in[30], *a_u3=d_in[31];
  const void *w_u4=d_in[32], *b_u4=d_in[33];

  const int NNODE = 625, E = 5000, CG = 256;

  // ---- batch-chunked, ws_size-adaptive layout (7.68 MB per batch element) ----
  // tail: deg(4KB incl. mode) + 4 transposed weight mats (fp32, 256KB each)
  int Bc = 16;
  while(Bc > 1 && (7680000L * Bc + 4096 + 4*262144L) > (long)ws_size) Bc >>= 1;

  char* wsb = (char*)d_ws;
  long o_xs1  = 2560000L * Bc;
  long o_BIGA = 3840000L * Bc;
  long o_BIGB = 6400000L * Bc;
  long o_deg  = 7680000L * Bc;
  bf16*  xs0 = (bf16*)wsb;                             // [d4 -> u4]
  bf16*  xs1 = (bf16*)(wsb + o_xs1);                   // [d3 -> u3]
  bf16*  xs2 = (bf16*)(wsb + o_BIGA);                  // [d2 -> u2]
  bf16*  xs3 = (bf16*)(wsb + o_BIGA +  640000L*Bc);    // [d1 -> u1]
  float* bot = (float*)(wsb + o_BIGA +  960000L*Bc);   // [bot -> u1] (=g2)
  float* xT  = (float*)(wsb + o_BIGA + 1600000L*Bc);   // [tr -> sage1]
  bf16*  u1  = (bf16*)(wsb + o_BIGA + 1600000L*Bc);    // alias xT (dead)
  bf16*  u3  = (bf16*)(wsb + o_BIGA);                  // alias BIGA (dead)
  float* agg = (float*)(wsb + o_BIGB);
  float* g1  = (float*)(wsb + o_BIGB +  640000L*Bc);   // [sage1 -> sage2]
  bf16*  u2  = (bf16*)(wsb + o_BIGB);                  // alias agg+g1 (dead)
  float* deg = (float*)(wsb + o_deg);                  // 625 fp32
  int*  mode = (int*)(wsb + o_deg + 3072);
  float* wlT1 = (float*)(wsb + o_deg + 4096);          // 4 x 65536 fp32
  float* wrT1 = wlT1 + 65536;
  float* wlT2 = wrT1 + 65536;
  float* wrT2 = wlT2 + 65536;
  float* g2  = bot;

  hipLaunchKernelGGL(k_detect, dim3(1), dim3(1), 0, stream, w_d4, mode);

  // one-time: degree + weight transposes (constant across chunks)
  hipMemsetAsync(deg, 0, NNODE*sizeof(float), stream);
  hipLaunchKernelGGL(k_deg, dim3(cdiv(E,256)), dim3(256), 0, stream, tgt, deg, E);
  hipLaunchKernelGGL(k_wtrans, dim3(256), dim3(256), 0, stream, wl1, wlT1, mode, CG);
  hipLaunchKernelGGL(k_wtrans, dim3(256), dim3(256), 0, stream, wr1, wrT1, mode, CG);
  hipLaunchKernelGGL(k_wtrans, dim3(256), dim3(256), 0, stream, wl2, wlT2, mode, CG);
  hipLaunchKernelGGL(k_wtrans, dim3(256), dim3(256), 0, stream, wr2, wrT2, mode, CG);

  for(int bo = 0; bo < 16; bo += Bc){
    long x_off   = (long)bo * 160000;   // 400*400 per sample
    long out_off = (long)bo * 320000;   // 2*400*400 per sample

    // ---- encoder ----
    { long n = (long)Bc*32*200*200;
      hipLaunchKernelGGL((k_conv3x3<2>), dim3(cdiv(n,256)), dim3(256), 0, stream,
                         x_in, x_off, 2, w_d4, b_d4, xs0, 0, mode, Bc, 1, 400, 400, 32, 200, 200);
      hipLaunchKernelGGL(k_inorm_prelu, dim3(Bc*32), dim3(256), 0, stream, xs0, 0, 40000, a_d4, mode); }
    { long n = (long)Bc*64*100*100;
      hipLaunchKernelGGL((k_conv3x3<2>), dim3(cdiv(n,256)), dim3(256), 0, stream,
                         xs0, 0, 0, w_d3, b_d3, xs1, 0, mode, Bc, 32, 200, 200, 64, 100, 100);
      hipLaunchKernelGGL(k_inorm_prelu, dim3(Bc*64), dim3(256), 0, stream, xs1, 0, 10000, a_d3, mode); }
    { long n = (long)Bc*128*50*50;
      hipLaunchKernelGGL((k_conv3x3<2>), dim3(cdiv(n,256)), dim3(256), 0, stream,
                         xs1, 0, 0, w_d2, b_d2, xs2, 0, mode, Bc, 64, 100, 100, 128, 50, 50);
      hipLaunchKernelGGL(k_inorm_prelu, dim3(Bc*128), dim3(256), 0, stream, xs2, 0, 2500, a_d2, mode); }
    { long n = (long)Bc*256*25*25;
      hipLaunchKernelGGL((k_conv3x3<2>), dim3(cdiv(n,256)), dim3(256), 0, stream,
                         xs2, 0, 0, w_d1, b_d1, xs3, 0, mode, Bc, 128, 50, 50, 256, 25, 25);
      hipLaunchKernelGGL(k_inorm_prelu, dim3(Bc*256), dim3(256), 0, stream, xs3, 0, 625, a_d1, mode); }
    { long n = (long)Bc*256*25*25;
      hipLaunchKernelGGL((k_conv3x3<1>), dim3(cdiv(n,256)), dim3(256), 0, stream,
                         xs3, 0, 0, w_bot, b_bot, bot, 1, mode, Bc, 256, 25, 25, 256, 25, 25);
      hipLaunchKernelGGL(k_inorm_prelu, dim3(Bc*256), dim3(256), 0, stream, bot, 1, 625, a_bot, mode); }

    // ---- GNN ----
    { long n = (long)Bc*CG*NNODE;
      hipLaunchKernelGGL(k_transpose, dim3(cdiv(n,256)), dim3(256), 0, stream, bot, xT, Bc, CG, NNODE); }
    hipMemsetAsync(agg, 0, 640000L*Bc, stream);
    hipLaunchKernelGGL(k_scatter, dim3(cdiv((long)E*CG,256)), dim3(256), 0, stream, xT, src, tgt, agg, E, CG, NNODE, Bc);
    hipLaunchKernelGGL(k_sage2, dim3(125, Bc), dim3(256), 0, stream,
                       xT, agg, deg, wlT1, wrT1, bl1, g1, mode, Bc, NNODE, CG, 0);
    hipMemsetAsync(agg, 0, 640000L*Bc, stream);
    hipLaunchKernelGGL(k_scatter, dim3(cdiv((long)E*CG,256)), dim3(256), 0, stream, g1, src, tgt, agg, E, CG, NNODE, Bc);
    hipLaunchKernelGGL(k_sage2, dim3(125, Bc), dim3(256), 0, stream,
                       g1, agg, deg, wlT2, wrT2, bl2, g2, mode, Bc, NNODE, CG, 1);

    // ---- decoder ----
    { long n = (long)Bc*128*50*50;
      hipLaunchKernelGGL(k_convT, dim3(cdiv(n,256)), dim3(256), 0, stream,
                         xs3, 0, 256, g2, 1, 256, w_u1, b_u1, u1, 0L, 0, mode, Bc, 25, 25, 128, 50, 50);
      hipLaunchKernelGGL(k_inorm_prelu, dim3(Bc*128), dim3(256), 0, stream, u1, 0, 2500, a_u1, mode); }
    { long n = (long)Bc*64*100*100;
      hipLaunchKernelGGL(k_convT, dim3(cdiv(n,256)), dim3(256), 0, stream,
                         xs2, 0, 128, u1, 0, 128, w_u2, b_u2, u2, 0L, 0, mode, Bc, 50, 50, 64, 100, 100);
      hipLaunchKernelGGL(k_inorm_prelu, dim3(Bc*64), dim3(256), 0, stream, u2, 0, 10000, a_u2, mode); }
    { long n = (long)Bc*32*200*200;
      hipLaunchKernelGGL(k_convT, dim3(cdiv(n,256)), dim3(256), 0, stream,
                         xs1, 0, 64, u2, 0, 64, w_u3, b_u3, u3, 0L, 0, mode, Bc, 100, 100, 32, 200, 200);
      hipLaunchKernelGGL(k_inorm_prelu, dim3(Bc*32), dim3(256), 0, stream, u3, 0, 40000, a_u3, mode); }
    { long n = (long)Bc*2*400*400;   // final: output dtype resolved from runtime mode
      hipLaunchKernelGGL(k_convT, dim3(cdiv(n,256)), dim3(256), 0, stream,
                         xs0, 0, 32, u3, 0, 32, w_u4, b_u4, d_out, out_off, 2, mode, Bc, 200, 200, 2, 400, 400); }
  }
}

// Round 6
// 24010.329 us; speedup vs baseline: 1.6534x; 1.2550x over previous
//
#include <hip/hip_runtime.h>
#include <hip/hip_bf16.h>

typedef __hip_bfloat16 bf16;

// flag f: 0 = bf16, 1 = fp32
static __device__ __forceinline__ float ldm(const void* p, long i, int f){
  return f ? ((const float*)p)[i] : __bfloat162float(((const bf16*)p)[i]);
}
static __device__ __forceinline__ void stm(void* p, long i, int f, float v){
  if(f) ((float*)p)[i] = v; else ((bf16*)p)[i] = __float2bfloat16(v);
}

// ---------------- input dtype detector (bit-level correct) ----------------
__global__ void k_detect(const void* __restrict__ w, int* __restrict__ mode){
  if(blockIdx.x == 0 && threadIdx.x == 0){
    const unsigned int* u = (const unsigned int*)w;
    int saneLo = 0;
    for(int i = 0; i < 64; i++){
      unsigned short lo = (unsigned short)(u[i] & 0xFFFFu);
      unsigned int fw = ((unsigned int)lo) << 16;
      float v; __builtin_memcpy(&v, &fw, 4);
      float a = fabsf(v);
      if(a > 1e-7f && a < 100.f) saneLo++;
    }
    *mode = (saneLo >= 48) ? 0 : 1;   // 0 = bf16, 1 = fp32
  }
}

// ---------------- weight transpose: wT[c][o] = w[o][c], fp32 out ----------------
__global__ void k_wtrans(const void* __restrict__ w, float* __restrict__ wT,
                         const int* __restrict__ dmode, int C){
  int idx = blockIdx.x * 256 + threadIdx.x;
  if(idx >= C * C) return;
  int dm = *dmode;
  int o = idx % C, c = idx / C;
  wT[idx] = ldm(w, (long)o * C + c, dm);
}

// ---------------- direct conv 3x3, pad 1, stride S ----------------
template<int S>
__global__ void k_conv3x3(const void* __restrict__ in, long in_off, int fin_sel,
                          const void* __restrict__ w, const void* __restrict__ bias,
                          void* __restrict__ out, int fout,
                          const int* __restrict__ dmode,
                          int B, int Cin, int Hin, int Win, int Cout, int Hout, int Wout)
{
  long idx = (long)blockIdx.x * 256 + threadIdx.x;
  long total = (long)B * Cout * Hout * Wout;
  if(idx >= total) return;
  int dm = *dmode;
  int fin = (fin_sel == 2) ? dm : fin_sel;
  int wo = (int)(idx % Wout); long t = idx / Wout;
  int ho = (int)(t % Hout);   t /= Hout;
  int co = (int)(t % Cout);   int b = (int)(t / Cout);
  float acc = ldm(bias, co, dm);
  int hbase = ho * S - 1, wbase = wo * S - 1;
  long wbi = (long)co * Cin * 9;
  long ibase = in_off + (long)b * Cin * Hin * Win;
  for(int ci = 0; ci < Cin; ci++){
    long ip = ibase + (long)ci * Hin * Win;
    long wp = wbi + (long)ci * 9;
    #pragma unroll
    for(int kh = 0; kh < 3; kh++){
      int hi = hbase + kh;
      if((unsigned)hi >= (unsigned)Hin) continue;
      long rp = ip + (long)hi * Win;
      #pragma unroll
      for(int kw = 0; kw < 3; kw++){
        int wi = wbase + kw;
        if((unsigned)wi >= (unsigned)Win) continue;
        acc += ldm(in, rp + wi, fin) * ldm(w, wp + kh*3 + kw, dm);
      }
    }
  }
  stm(out, idx, fout, acc);
}

// ---------------- InstanceNorm (affine=False) + PReLU, in place ----------------
__global__ void k_inorm_prelu(void* __restrict__ x, int f, int HW,
                              const void* __restrict__ a, const int* __restrict__ dmode)
{
  int dm = *dmode;
  long base = (long)blockIdx.x * HW;
  float s = 0.f, s2 = 0.f;
  for(int i = threadIdx.x; i < HW; i += 256){ float v = ldm(x, base + i, f); s += v; s2 += v*v; }
  __shared__ float sh[256], sh2[256];
  sh[threadIdx.x] = s; sh2[threadIdx.x] = s2; __syncthreads();
  for(int off = 128; off > 0; off >>= 1){
    if(threadIdx.x < off){ sh[threadIdx.x] += sh[threadIdx.x+off]; sh2[threadIdx.x] += sh2[threadIdx.x+off]; }
    __syncthreads();
  }
  float mean = sh[0] / HW;
  float var  = sh2[0] / HW - mean * mean;
  float inv  = rsqrtf(fmaxf(var, 0.f) + 1e-5f);
  float alpha = ldm(a, 0, dm);
  for(int i = threadIdx.x; i < HW; i += 256){
    float v = (ldm(x, base + i, f) - mean) * inv;
    stm(x, base + i, f, v >= 0.f ? v : alpha * v);
  }
}

// ---------------- transpose [B,C,N] -> [B,N,C] (fp32) ----------------
__global__ void k_transpose(const float* __restrict__ in, float* __restrict__ out, int B, int C, int N){
  long idx = (long)blockIdx.x * 256 + threadIdx.x;
  long total = (long)B * C * N; if(idx >= total) return;
  int c = (int)(idx % C); long t = idx / C; int n = (int)(t % N); int b = (int)(t / N);
  out[idx] = in[((long)b * C + c) * N + n];
}

// ---------------- degree ----------------
__global__ void k_deg(const int* __restrict__ tgt, float* __restrict__ deg, int E){
  int e = blockIdx.x * 256 + threadIdx.x;
  if(e < E) atomicAdd(&deg[tgt[e]], 1.0f);
}

// ---------------- scatter add: agg[b,tgt,c] += x[b,src,c]  ([B,N,C] fp32) ----------------
__global__ void k_scatter(const float* __restrict__ xT, const int* __restrict__ src,
                          const int* __restrict__ tgt, float* __restrict__ agg,
                          int E, int C, int N, int B)
{
  int t = blockIdx.x * 256 + threadIdx.x;
  if(t >= E * C) return;
  int c = t % C; int e = t / C;
  int s = src[e], d = tgt[e];
  for(int b = 0; b < B; b++){
    atomicAdd(&agg[((long)b * N + d) * C + c], xT[((long)b * N + s) * C + c]);
  }
}

// ---------------- SAGE as tiled GEMM ----------------
#define TN 5
__global__ void k_sage2(const float* __restrict__ xT, const float* __restrict__ agg,
                        const float* __restrict__ deg,
                        const float* __restrict__ wlT, const float* __restrict__ wrT,
                        const void* __restrict__ bl,
                        float* __restrict__ out, const int* __restrict__ dmode,
                        int B, int N, int C, int transpose_out)
{
  int o  = threadIdx.x;
  int n0 = blockIdx.x * TN;
  int b  = blockIdx.y;
  __shared__ float sX[TN][256];
  __shared__ float sA[TN][256];
  #pragma unroll
  for(int j = 0; j < TN; j++){
    int n = n0 + j;
    float dinv = 1.0f / fmaxf(deg[n], 1.0f);
    long base = ((long)b * N + n) * C;
    sX[j][o] = xT[base + o];
    sA[j][o] = agg[base + o] * dinv;
  }
  __syncthreads();
  int dm = *dmode;
  float bv = ldm(bl, o, dm);
  float acc[TN];
  #pragma unroll
  for(int j = 0; j < TN; j++) acc[j] = bv;
  #pragma unroll 4
  for(int c = 0; c < 256; c++){
    float wlv = wlT[(long)c * 256 + o];
    float wrv = wrT[(long)c * 256 + o];
    #pragma unroll
    for(int j = 0; j < TN; j++){
      acc[j] += sA[j][c] * wlv + sX[j][c] * wrv;
    }
  }
  #pragma unroll
  for(int j = 0; j < TN; j++){
    int n = n0 + j;
    float v = fmaxf(acc[j], 0.f);
    if(transpose_out) out[((long)b * C + o) * N + n] = v;
    else              out[((long)b * N + n) * C + o] = v;
  }
}

// ---------------- ConvTranspose2d k=3 s=2 p=1 op=1 — parity-decomposed, LDS-tiled ----------------
// out[2i  ][2j  ] += in[i][j]*w11
// out[2i  ][2j+1] += in[i][j]*w12 + in[i][j+1]*w10
// out[2i+1][2j  ] += in[i][j]*w21 + in[i+1][j]*w01
// out[2i+1][2j+1] += in[i][j]*w22 + in[i][j+1]*w20 + in[i+1][j]*w02 + in[i+1][j+1]*w00
// (w[kh][kw], hi=(ho+1-kh)/2; zero-padded halo exactly drops edge taps)
// Block: CT co x RT input rows; each thread covers 8 input cols -> 2x16 outputs.
// CC input channels staged per barrier pair. Requires Cin % CC == 0.
template<int CT, int RT, int CC>
__global__ void k_convT2(const void* __restrict__ inA, int fA, int C1,
                         const void* __restrict__ inB, int fB, int C2,
                         const void* __restrict__ w, const void* __restrict__ bias,
                         void* __restrict__ out, long out_off, int fout_sel,
                         const int* __restrict__ dmode,
                         int Hin, int Win, int Cout, int ntj)
{
  __shared__ float sIn[CC][(RT+1)*9];
  __shared__ float sWf[CC][CT*9];
  int tid = threadIdx.x;
  int col = tid % CT;               // co within tile
  int r   = tid / CT;               // input row within tile
  int ti  = blockIdx.x / ntj, tj = blockIdx.x % ntj;
  int i0  = ti * RT, j0 = tj * 8;
  int co0 = blockIdx.y * CT;
  int b   = blockIdx.z;
  int co  = co0 + col;
  int dm  = *dmode;
  int fout = (fout_sel == 2) ? dm : fout_sel;
  int Cin = C1 + C2;
  int Hout = 2*Hin, Wout = 2*Win;

  float acc0[16], acc1[16];
  #pragma unroll
  for(int c = 0; c < 16; c++){ acc0[c] = 0.f; acc1[c] = 0.f; }

  for(int ci0 = 0; ci0 < Cin; ci0 += CC){
    // stage input tile (RT+1)x9 per ci, zero-padded OOB
    for(int e = tid; e < CC*(RT+1)*9; e += 256){
      int s = e / ((RT+1)*9); int rem = e % ((RT+1)*9);
      int rr = rem / 9, cc = rem % 9;
      int ci = ci0 + s;
      int ii = i0 + rr, jj = j0 + cc;
      float v = 0.f;
      if(ii < Hin && jj < Win){
        if(ci < C1) v = ldm(inA, ((long)b*C1 + ci)*Hin*Win + (long)ii*Win + jj, fA);
        else        v = ldm(inB, ((long)b*C2 + (ci-C1))*Hin*Win + (long)ii*Win + jj, fB);
      }
      sIn[s][rem] = v;
    }
    // stage weights: per ci, contiguous [co0..co0+CT)x9 slice
    for(int e = tid; e < CC*CT*9; e += 256){
      int s = e / (CT*9); int rem = e % (CT*9);
      int ci = ci0 + s;
      sWf[s][rem] = ldm(w, ((long)ci*Cout + co0)*9 + rem, dm);
    }
    __syncthreads();
    #pragma unroll
    for(int s = 0; s < CC; s++){
      float wv[9];
      #pragma unroll
      for(int k = 0; k < 9; k++) wv[k] = sWf[s][col*9 + k];
      float x0[9], x1[9];
      #pragma unroll
      for(int c = 0; c < 9; c++){ x0[c] = sIn[s][r*9 + c]; x1[c] = sIn[s][(r+1)*9 + c]; }
      #pragma unroll
      for(int jj = 0; jj < 8; jj++){
        float a00 = x0[jj], a01 = x0[jj+1], a10 = x1[jj], a11 = x1[jj+1];
        acc0[2*jj]   += a00*wv[4];
        acc0[2*jj+1] += a00*wv[5] + a01*wv[3];
        acc1[2*jj]   += a00*wv[7] + a10*wv[1];
        acc1[2*jj+1] += a00*wv[8] + a01*wv[6] + a10*wv[2] + a11*wv[0];
      }
    }
    __syncthreads();
  }

  int i = i0 + r;
  if(i < Hin){
    float bv = ldm(bias, co, dm);
    long base0 = (((long)b*Cout + co)*Hout + 2*i) * Wout + 2*j0;
    #pragma unroll
    for(int c = 0; c < 16; c++){
      if(j0 + (c >> 1) < Win){
        stm(out, out_off + base0 + c,        fout, acc0[c] + bv);
        stm(out, out_off + base0 + Wout + c, fout, acc1[c] + bv);
      }
    }
  }
}

static inline int cdiv(long a, long b){ return (int)((a + b - 1) / b); }

extern "C" void kernel_launch(void* const* d_in, const int* in_sizes, int n_in,
                              void* d_out, int out_size, void* d_ws, size_t ws_size,
                              hipStream_t stream) {
  const void* x_in  = d_in[0];
  const int*  edges = (const int*)d_in[1];
  const int* src = edges;          // edges[0,:]
  const int* tgt = edges + 5000;   // edges[1,:]
  const void *w_d4=d_in[2],  *b_d4=d_in[3],  *a_d4=d_in[4];
  const void *w_d3=d_in[5],  *b_d3=d_in[6],  *a_d3=d_in[7];
  const void *w_d2=d_in[8],  *b_d2=d_in[9],  *a_d2=d_in[10];
  const void *w_d1=d_in[11], *b_d1=d_in[12], *a_d1=d_in[13];
  const void *w_bot=d_in[14],*b_bot=d_in[15],*a_bot=d_in[16];
  const void *wl1=d_in[17], *bl1=d_in[18], *wr1=d_in[19];
  const void *wl2=d_in[20], *bl2=d_in[21], *wr2=d_in[22];
  const void *w_u1=d_in[23], *b_u1=d_in[24], *a_u1=d_in[25];
  const void *w_u2=d_in[26], *b_u2=d_in[27], *a_u2=d_in[28];
  const void *w_u3=d_in[29], *b_u3=d_in[30], *a_u3=d_in[31];
  const void *w_u4=d_in[32], *b_u4=d_in[33];

  const int NNODE = 625, E = 5000, CG = 256;

  int Bc = 16;
  while(Bc > 1 && (7680000L * Bc + 4096 + 4*262144L) > (long)ws_size) Bc >>= 1;

  char* wsb = (char*)d_ws;
  long o_xs1  = 2560000L * Bc;
  long o_BIGA = 3840000L * Bc;
  long o_BIGB = 6400000L * Bc;
  long o_deg  = 7680000L * Bc;
  bf16*  xs0 = (bf16*)wsb;                             // [d4 -> u4]
  bf16*  xs1 = (bf16*)(wsb + o_xs1);                   // [d3 -> u3]
  bf16*  xs2 = (bf16*)(wsb + o_BIGA);                  // [d2 -> u2]
  bf16*  xs3 = (bf16*)(wsb + o_BIGA +  640000L*Bc);    // [d1 -> u1]
  float* bot = (float*)(wsb + o_BIGA +  960000L*Bc);   // [bot -> u1] (=g2)
  float* xT  = (float*)(wsb + o_BIGA + 1600000L*Bc);   // [tr -> sage1]
  bf16*  u1  = (bf16*)(wsb + o_BIGA + 1600000L*Bc);    // alias xT (dead)
  bf16*  u3  = (bf16*)(wsb + o_BIGA);                  // alias BIGA (dead)
  float* agg = (float*)(wsb + o_BIGB);
  float* g1  = (float*)(wsb + o_BIGB +  640000L*Bc);   // [sage1 -> sage2]
  bf16*  u2  = (bf16*)(wsb + o_BIGB);                  // alias agg+g1 (dead)
  float* deg = (float*)(wsb + o_deg);                  // 625 fp32
  int*  mode = (int*)(wsb + o_deg + 3072);
  float* wlT1 = (float*)(wsb + o_deg + 4096);          // 4 x 65536 fp32
  float* wrT1 = wlT1 + 65536;
  float* wlT2 = wrT1 + 65536;
  float* wrT2 = wlT2 + 65536;
  float* g2  = bot;

  hipLaunchKernelGGL(k_detect, dim3(1), dim3(1), 0, stream, w_d4, mode);

  hipMemsetAsync(deg, 0, NNODE*sizeof(float), stream);
  hipLaunchKernelGGL(k_deg, dim3(cdiv(E,256)), dim3(256), 0, stream, tgt, deg, E);
  hipLaunchKernelGGL(k_wtrans, dim3(256), dim3(256), 0, stream, wl1, wlT1, mode, CG);
  hipLaunchKernelGGL(k_wtrans, dim3(256), dim3(256), 0, stream, wr1, wrT1, mode, CG);
  hipLaunchKernelGGL(k_wtrans, dim3(256), dim3(256), 0, stream, wl2, wlT2, mode, CG);
  hipLaunchKernelGGL(k_wtrans, dim3(256), dim3(256), 0, stream, wr2, wrT2, mode, CG);

  for(int bo = 0; bo < 16; bo += Bc){
    long x_off   = (long)bo * 160000;
    long out_off = (long)bo * 320000;

    // ---- encoder ----
    { long n = (long)Bc*32*200*200;
      hipLaunchKernelGGL((k_conv3x3<2>), dim3(cdiv(n,256)), dim3(256), 0, stream,
                         x_in, x_off, 2, w_d4, b_d4, xs0, 0, mode, Bc, 1, 400, 400, 32, 200, 200);
      hipLaunchKernelGGL(k_inorm_prelu, dim3(Bc*32), dim3(256), 0, stream, xs0, 0, 40000, a_d4, mode); }
    { long n = (long)Bc*64*100*100;
      hipLaunchKernelGGL((k_conv3x3<2>), dim3(cdiv(n,256)), dim3(256), 0, stream,
                         xs0, 0, 0, w_d3, b_d3, xs1, 0, mode, Bc, 32, 200, 200, 64, 100, 100);
      hipLaunchKernelGGL(k_inorm_prelu, dim3(Bc*64), dim3(256), 0, stream, xs1, 0, 10000, a_d3, mode); }
    { long n = (long)Bc*128*50*50;
      hipLaunchKernelGGL((k_conv3x3<2>), dim3(cdiv(n,256)), dim3(256), 0, stream,
                         xs1, 0, 0, w_d2, b_d2, xs2, 0, mode, Bc, 64, 100, 100, 128, 50, 50);
      hipLaunchKernelGGL(k_inorm_prelu, dim3(Bc*128), dim3(256), 0, stream, xs2, 0, 2500, a_d2, mode); }
    { long n = (long)Bc*256*25*25;
      hipLaunchKernelGGL((k_conv3x3<2>), dim3(cdiv(n,256)), dim3(256), 0, stream,
                         xs2, 0, 0, w_d1, b_d1, xs3, 0, mode, Bc, 128, 50, 50, 256, 25, 25);
      hipLaunchKernelGGL(k_inorm_prelu, dim3(Bc*256), dim3(256), 0, stream, xs3, 0, 625, a_d1, mode); }
    { long n = (long)Bc*256*25*25;
      hipLaunchKernelGGL((k_conv3x3<1>), dim3(cdiv(n,256)), dim3(256), 0, stream,
                         xs3, 0, 0, w_bot, b_bot, bot, 1, mode, Bc, 256, 25, 25, 256, 25, 25);
      hipLaunchKernelGGL(k_inorm_prelu, dim3(Bc*256), dim3(256), 0, stream, bot, 1, 625, a_bot, mode); }

    // ---- GNN ----
    { long n = (long)Bc*CG*NNODE;
      hipLaunchKernelGGL(k_transpose, dim3(cdiv(n,256)), dim3(256), 0, stream, bot, xT, Bc, CG, NNODE); }
    hipMemsetAsync(agg, 0, 640000L*Bc, stream);
    hipLaunchKernelGGL(k_scatter, dim3(cdiv((long)E*CG,256)), dim3(256), 0, stream, xT, src, tgt, agg, E, CG, NNODE, Bc);
    hipLaunchKernelGGL(k_sage2, dim3(125, Bc), dim3(256), 0, stream,
                       xT, agg, deg, wlT1, wrT1, bl1, g1, mode, Bc, NNODE, CG, 0);
    hipMemsetAsync(agg, 0, 640000L*Bc, stream);
    hipLaunchKernelGGL(k_scatter, dim3(cdiv((long)E*CG,256)), dim3(256), 0, stream, g1, src, tgt, agg, E, CG, NNODE, Bc);
    hipLaunchKernelGGL(k_sage2, dim3(125, Bc), dim3(256), 0, stream,
                       g1, agg, deg, wlT2, wrT2, bl2, g2, mode, Bc, NNODE, CG, 1);

    // ---- decoder (parity-decomposed convT) ----
    // u1: 25x25, Cin 512 (xs3 bf16 + g2 fp32) -> 128 @ 50x50
    hipLaunchKernelGGL((k_convT2<32,8,8>), dim3(4*4, 128/32, Bc), dim3(256), 0, stream,
                       xs3, 0, 256, g2, 1, 256, w_u1, b_u1, u1, 0L, 0, mode, 25, 25, 128, 4);
    hipLaunchKernelGGL(k_inorm_prelu, dim3(Bc*128), dim3(256), 0, stream, u1, 0, 2500, a_u1, mode);
    // u2: 50x50, Cin 256 -> 64 @ 100x100
    hipLaunchKernelGGL((k_convT2<32,8,8>), dim3(7*7, 64/32, Bc), dim3(256), 0, stream,
                       xs2, 0, 128, u1, 0, 128, w_u2, b_u2, u2, 0L, 0, mode, 50, 50, 64, 7);
    hipLaunchKernelGGL(k_inorm_prelu, dim3(Bc*64), dim3(256), 0, stream, u2, 0, 10000, a_u2, mode);
    // u3: 100x100, Cin 128 -> 32 @ 200x200
    hipLaunchKernelGGL((k_convT2<32,8,8>), dim3(13*13, 1, Bc), dim3(256), 0, stream,
                       xs1, 0, 64, u2, 0, 64, w_u3, b_u3, u3, 0L, 0, mode, 100, 100, 32, 13);
    hipLaunchKernelGGL(k_inorm_prelu, dim3(Bc*32), dim3(256), 0, stream, u3, 0, 40000, a_u3, mode);
    // u4: 200x200, Cin 64 -> 2 @ 400x400 (Cout=2 -> CT=2, RT=128)
    hipLaunchKernelGGL((k_convT2<2,128,4>), dim3(2*25, 1, Bc), dim3(256), 0, stream,
                       xs0, 0, 32, u3, 0, 32, w_u4, b_u4, d_out, out_off, 2, mode, 200, 200, 2, 25);
  }
}